// Round 6
// baseline (617.149 us; speedup 1.0000x reference)
//
#include <hip/hip_runtime.h>

#define E_EDGES 480000
#define N_NODES 30000
#define IN_DIM 256
#define REL_DIM 128
#define OUT_DIM 512
#define CAT_DIM 640  /* 2*IN_DIM + REL_DIM */
#define MTILES 1875  /* 30000/16 */

typedef float f32x4 __attribute__((ext_vector_type(4)));
typedef __bf16 bf16x8 __attribute__((ext_vector_type(8)));
typedef unsigned short u16x8 __attribute__((ext_vector_type(8)));

static __device__ __forceinline__ unsigned short f2bf(float x) {
    union { float f; unsigned int u; } c; c.f = x;
    unsigned int u = c.u;
    unsigned int r = u + 0x7fffu + ((u >> 16) & 1u);
    return (unsigned short)(r >> 16);
}
static __device__ __forceinline__ float bf2f(unsigned short b) {
    union { unsigned int u; float f; } c; c.u = ((unsigned int)b) << 16;
    return c.f;
}

// ---------------------------------------------------------------------------
// CSR construction
// ---------------------------------------------------------------------------
__global__ void k_count(const int* __restrict__ dst, int* __restrict__ cnt) {
    int e = blockIdx.x * 256 + threadIdx.x;
    if (e < E_EDGES) atomicAdd(&cnt[dst[e]], 1);
}

__global__ void k_scan(const int* __restrict__ cnt, int* __restrict__ off,
                       int* __restrict__ cur) {
    __shared__ int part[1024];
    const int t = threadIdx.x;
    const int CH = (N_NODES + 1023) / 1024;  // 30
    int b = t * CH;
    int e = b + CH; if (e > N_NODES) e = N_NODES;
    if (b > N_NODES) b = N_NODES;
    int s = 0;
    for (int i = b; i < e; ++i) s += cnt[i];
    part[t] = s;
    __syncthreads();
    for (int d = 1; d < 1024; d <<= 1) {
        int v = (t >= d) ? part[t - d] : 0;
        __syncthreads();
        part[t] += v;
        __syncthreads();
    }
    int run = part[t] - s;  // exclusive prefix of this chunk
    for (int i = b; i < e; ++i) { off[i] = run; cur[i] = run; run += cnt[i]; }
    if (t == 1023) off[N_NODES] = run;
}

// fill: csr-ordered packed edge records {eid, src, eatt, natt[src]}
__global__ void k_fill(const int* __restrict__ dst, const int* __restrict__ src,
                       const float* __restrict__ eatt, const float* __restrict__ natt,
                       int* __restrict__ cur, int4* __restrict__ ecp) {
    int e = blockIdx.x * 256 + threadIdx.x;
    if (e < E_EDGES) {
        const int d = dst[e];
        const int s = src[e];
        const int p = atomicAdd(&cur[d], 1);
        ecp[p] = make_int4(e, s, __float_as_int(eatt[e]), __float_as_int(natt[s]));
    }
}

// ---------------------------------------------------------------------------
// Prep: convert Wn/Wr/Wa f32 -> pre-swizzled bf16 MFMA-B fragment tables.
// Frag layout: table[((kb*4+g)*N + c)*8 + j] = bf16(B[kb*32 + g*8 + j][c]).
// Reader lane l (for col-tile nt, k-block kb): c = nc0+nt*16+(l&15), g=l>>4.
// Frag counts: Wn 8*4*256=8192, Wr 4*4*128=2048, Wa 20*4*512=40960.
// ---------------------------------------------------------------------------
__global__ void k_prep(const float* __restrict__ Wn, const float* __restrict__ Wr,
                       const float* __restrict__ Wa,
                       unsigned short* __restrict__ WnT,
                       unsigned short* __restrict__ WrT,
                       unsigned short* __restrict__ WaT) {
    const int fid = blockIdx.x * 256 + threadIdx.x;
    const float* Bg; unsigned short* WT; int N; int idx;
    if (fid < 8192)        { Bg = Wn; WT = WnT; N = 256; idx = fid; }
    else if (fid < 10240)  { Bg = Wr; WT = WrT; N = 128; idx = fid - 8192; }
    else if (fid < 51200)  { Bg = Wa; WT = WaT; N = 512; idx = fid - 10240; }
    else return;
    const int c = idx % N;
    const int t = idx / N;     // kb*4 + g
    const int k0 = t * 8;      // (kb*32 + g*8)
    u16x8 v;
#pragma unroll
    for (int j = 0; j < 8; ++j) v[j] = f2bf(Bg[(size_t)(k0 + j) * N + c]);
    *(u16x8*)(WT + (size_t)idx * 8) = v;
}

// ---------------------------------------------------------------------------
// LDS-free A-stationary GEMM: C_bf16[M,N] = A_f32[M,K] @ B(table) + epilogue
//   v = acc + (rowb ? rowb[row]*bias[col] : bias[col])
// 8 waves/block, one 16-row m-tile per wave; A-frags bf16 in regs (read once);
// B-frags loaded per-use from L2-resident pre-swizzled table.
// MFMA 16x16x32 bf16; D lane l reg r -> row (l>>4)*4+r, col l&15.
// ---------------------------------------------------------------------------
template <int K, int N>
__launch_bounds__(512)
__global__ void gemm_reg(const float* __restrict__ Ag,
                         const unsigned short* __restrict__ Btab,
                         const float* __restrict__ bias,
                         const float* __restrict__ rowb,
                         unsigned short* __restrict__ Cg,
                         int ldc, int mtiles) {
    constexpr int KB = K / 32;
    constexpr int NT = N / 16;
    const int lane = threadIdx.x & 63;
    const int wave = threadIdx.x >> 6;
    const int row16 = lane & 15;
    const int kgrp = lane >> 4;
    const int mt = blockIdx.x * 8 + wave;
    const bool active = (mt < mtiles);

    // load + convert A fragments once
    bf16x8 af[KB];
    {
        const float* arow = Ag + (size_t)((active ? mt : 0) * 16 + row16) * K + kgrp * 8;
#pragma unroll
        for (int kb = 0; kb < KB; ++kb) {
            f32x4 x0 = *(const f32x4*)(arow + kb * 32);
            f32x4 x1 = *(const f32x4*)(arow + kb * 32 + 4);
            u16x8 au;
#pragma unroll
            for (int j = 0; j < 4; ++j) { au[j] = f2bf(x0[j]); au[4 + j] = f2bf(x1[j]); }
            af[kb] = __builtin_bit_cast(bf16x8, au);
        }
    }

    const unsigned short* pB = Btab + (size_t)(kgrp * N + row16) * 8;
    f32x4 acc[NT] = {};
#pragma unroll
    for (int kb = 0; kb < KB; ++kb) {
        const unsigned short* pBk = pB + (size_t)kb * 4 * N * 8;
#pragma unroll
        for (int nt = 0; nt < NT; ++nt) {
            bf16x8 bf = *(const bf16x8*)(pBk + nt * 128);
            acc[nt] = __builtin_amdgcn_mfma_f32_16x16x32_bf16(af[kb], bf, acc[nt], 0, 0, 0);
        }
    }
    if (active) {
#pragma unroll
        for (int nt = 0; nt < NT; ++nt) {
            const int ocol = nt * 16 + row16;
            const float bv = bias[ocol];
#pragma unroll
            for (int r = 0; r < 4; ++r) {
                const int orow = mt * 16 + kgrp * 4 + r;
                float v = acc[nt][r] + (rowb ? rowb[orow] * bv : bv);
                Cg[(size_t)orow * ldc + ocol] = f2bf(v);
            }
        }
    }
}

// ---------------------------------------------------------------------------
// Gather/reduce over CSR (packed records, 4-deep ILP): per dst node n,
//   Amat[n, 256:512] = bf16( sum_e natt[src_e]*h2[src_e] + deg*natt[n]*h2[n] )
//   R[n, 0:128]      = f32 ( sum_e eatt[e]*rel[e] )
//   S[n]             = sum_e eatt[e]
// ---------------------------------------------------------------------------
__launch_bounds__(128)
__global__ void k_gather(unsigned short* __restrict__ Amat,
                         const float* __restrict__ rel,
                         const float* __restrict__ natt,
                         const int* __restrict__ off,
                         const int4* __restrict__ ecp,
                         float* __restrict__ R,
                         float* __restrict__ S) {
    const int n = blockIdx.x;
    const int t = threadIdx.x;  // 0..127
    const int b = off[n], e = off[n + 1];
    float a0 = 0.f, a1 = 0.f, ar = 0.f, ae = 0.f;
    int i = b;
    for (; i + 4 <= e; i += 4) {
        const int4 p0 = ecp[i];
        const int4 p1 = ecp[i + 1];
        const int4 p2 = ecp[i + 2];
        const int4 p3 = ecp[i + 3];
        const unsigned int hv0 = *(const unsigned int*)(Amat + (size_t)p0.y * CAT_DIM + 2 * t);
        const unsigned int hv1 = *(const unsigned int*)(Amat + (size_t)p1.y * CAT_DIM + 2 * t);
        const unsigned int hv2 = *(const unsigned int*)(Amat + (size_t)p2.y * CAT_DIM + 2 * t);
        const unsigned int hv3 = *(const unsigned int*)(Amat + (size_t)p3.y * CAT_DIM + 2 * t);
        const float r0 = rel[(size_t)p0.x * REL_DIM + t];
        const float r1 = rel[(size_t)p1.x * REL_DIM + t];
        const float r2 = rel[(size_t)p2.x * REL_DIM + t];
        const float r3 = rel[(size_t)p3.x * REL_DIM + t];
        const float ea0 = __int_as_float(p0.z), w0 = __int_as_float(p0.w);
        const float ea1 = __int_as_float(p1.z), w1 = __int_as_float(p1.w);
        const float ea2 = __int_as_float(p2.z), w2 = __int_as_float(p2.w);
        const float ea3 = __int_as_float(p3.z), w3 = __int_as_float(p3.w);
        a0 += w0 * bf2f((unsigned short)(hv0 & 0xffffu)) + w1 * bf2f((unsigned short)(hv1 & 0xffffu))
            + w2 * bf2f((unsigned short)(hv2 & 0xffffu)) + w3 * bf2f((unsigned short)(hv3 & 0xffffu));
        a1 += w0 * bf2f((unsigned short)(hv0 >> 16)) + w1 * bf2f((unsigned short)(hv1 >> 16))
            + w2 * bf2f((unsigned short)(hv2 >> 16)) + w3 * bf2f((unsigned short)(hv3 >> 16));
        ar += ea0 * r0 + ea1 * r1 + ea2 * r2 + ea3 * r3;
        ae += ea0 + ea1 + ea2 + ea3;
    }
    for (; i < e; ++i) {
        const int4 p0 = ecp[i];
        const unsigned int hv0 = *(const unsigned int*)(Amat + (size_t)p0.y * CAT_DIM + 2 * t);
        const float r0 = rel[(size_t)p0.x * REL_DIM + t];
        const float ea0 = __int_as_float(p0.z), w0 = __int_as_float(p0.w);
        a0 += w0 * bf2f((unsigned short)(hv0 & 0xffffu));
        a1 += w0 * bf2f((unsigned short)(hv0 >> 16));
        ar += ea0 * r0;
        ae += ea0;
    }
    const int deg = e - b;
    if (deg > 0) {
        const float w = (float)deg * natt[n];
        const unsigned int hv = *(const unsigned int*)(Amat + (size_t)n * CAT_DIM + 2 * t);
        a0 += w * bf2f((unsigned short)(hv & 0xffffu));
        a1 += w * bf2f((unsigned short)(hv >> 16));
    }
    const unsigned int packed = (unsigned int)f2bf(a0) | ((unsigned int)f2bf(a1) << 16);
    *(unsigned int*)(Amat + (size_t)n * CAT_DIM + IN_DIM + 2 * t) = packed;
    R[(size_t)n * REL_DIM + t] = ar;
    if (t == 0) S[n] = ae;
}

// ---------------------------------------------------------------------------
// Final GEMM (LDS-free): out_f32[30000,512] = relu(A_bf16[30000,640] @ Wa + ba)
// 8 waves x 2 m-tiles/wave (BM=256), BN=256 (y=2). B-frags from WaT (L2).
// Per kb-step: 2 A-loads + 16 B-loads vs 32 MFMA.
// ---------------------------------------------------------------------------
__launch_bounds__(512)
__global__ void gemm_final(const unsigned short* __restrict__ Ag,
                           const unsigned short* __restrict__ WaT,
                           const float* __restrict__ ba,
                           float* __restrict__ out) {
    const int lane = threadIdx.x & 63;
    const int wave = threadIdx.x >> 6;
    const int row16 = lane & 15;
    const int kgrp = lane >> 4;
    const int nc0 = blockIdx.y * 256;
    const int mt0 = blockIdx.x * 16 + wave * 2;
    const int mt1 = mt0 + 1;
    const bool act0 = (mt0 < MTILES);
    const bool act1 = (mt1 < MTILES);

    f32x4 acc0[16] = {};
    f32x4 acc1[16] = {};
    const unsigned short* arow0 =
        Ag + (size_t)((act0 ? mt0 : 0) * 16 + row16) * CAT_DIM + kgrp * 8;
    const unsigned short* arow1 =
        Ag + (size_t)((act1 ? mt1 : 0) * 16 + row16) * CAT_DIM + kgrp * 8;
    const unsigned short* pB = WaT + (size_t)(kgrp * OUT_DIM + nc0 + row16) * 8;

#pragma unroll
    for (int kb = 0; kb < CAT_DIM / 32; ++kb) {
        bf16x8 a0 = __builtin_bit_cast(bf16x8, *(const u16x8*)(arow0 + kb * 32));
        bf16x8 a1 = __builtin_bit_cast(bf16x8, *(const u16x8*)(arow1 + kb * 32));
        const unsigned short* pBk = pB + (size_t)kb * 4 * OUT_DIM * 8;
#pragma unroll
        for (int nt = 0; nt < 16; ++nt) {
            bf16x8 bf = *(const bf16x8*)(pBk + nt * 128);
            acc0[nt] = __builtin_amdgcn_mfma_f32_16x16x32_bf16(a0, bf, acc0[nt], 0, 0, 0);
            acc1[nt] = __builtin_amdgcn_mfma_f32_16x16x32_bf16(a1, bf, acc1[nt], 0, 0, 0);
        }
    }
    if (act0) {
#pragma unroll
        for (int nt = 0; nt < 16; ++nt) {
            const int ocol = nc0 + nt * 16 + row16;
            const float bv = ba[ocol];
#pragma unroll
            for (int r = 0; r < 4; ++r) {
                const int orow = mt0 * 16 + kgrp * 4 + r;
                out[(size_t)orow * OUT_DIM + ocol] = fmaxf(acc0[nt][r] + bv, 0.0f);
            }
        }
    }
    if (act1) {
#pragma unroll
        for (int nt = 0; nt < 16; ++nt) {
            const int ocol = nc0 + nt * 16 + row16;
            const float bv = ba[ocol];
#pragma unroll
            for (int r = 0; r < 4; ++r) {
                const int orow = mt1 * 16 + kgrp * 4 + r;
                out[(size_t)orow * OUT_DIM + ocol] = fmaxf(acc1[nt][r] + bv, 0.0f);
            }
        }
    }
}

// ---------------------------------------------------------------------------
extern "C" void kernel_launch(void* const* d_in, const int* in_sizes, int n_in,
                              void* d_out, int out_size, void* d_ws, size_t ws_size,
                              hipStream_t stream) {
    const float* h    = (const float*)d_in[0];
    const float* natt = (const float*)d_in[1];
    const float* rel  = (const float*)d_in[2];
    const float* eatt = (const float*)d_in[3];
    const float* Wn   = (const float*)d_in[4];
    const float* bn   = (const float*)d_in[5];
    const float* Wr   = (const float*)d_in[6];
    const float* br   = (const float*)d_in[7];
    const float* Wa   = (const float*)d_in[8];
    const float* ba   = (const float*)d_in[9];
    const int* src    = (const int*)d_in[10];
    const int* dst    = (const int*)d_in[11];
    float* out = (float*)d_out;

    // workspace layout (bytes, all 16B-aligned)
    char* base = (char*)d_ws;
    unsigned short* Amat = (unsigned short*)(base);          // 30000*640*2 = 38,400,000
    float* R = (float*)(base + 38400000);                    // 15,360,000
    float* S = (float*)(base + 53760000);                    // 120,000
    int* cnt = (int*)(base + 53880064);                      // 120,000
    int* off = (int*)(base + 54000064);                      // 120,004
    int* cur = (int*)(base + 54120128);                      // 120,000
    int4* ecp = (int4*)(base + 54240128);                    // 7,680,000
    unsigned short* WnT = (unsigned short*)(base + 61920128);  // 131,072
    unsigned short* WrT = (unsigned short*)(base + 62051200);  // 32,768
    unsigned short* WaT = (unsigned short*)(base + 62083968);  // 655,360

    // CSR build + weight prep
    hipMemsetAsync(cnt, 0, N_NODES * sizeof(int), stream);
    k_count<<<(E_EDGES + 255) / 256, 256, 0, stream>>>(dst, cnt);
    k_scan<<<1, 1024, 0, stream>>>(cnt, off, cur);
    k_fill<<<(E_EDGES + 255) / 256, 256, 0, stream>>>(dst, src, eatt, natt, cur, ecp);
    k_prep<<<200, 256, 0, stream>>>(Wn, Wr, Wa, WnT, WrT, WaT);

    // h2 = h @ Wn + bn  -> Amat[:, 0:256] (bf16)
    gemm_reg<256, 256><<<235, 512, 0, stream>>>(h, WnT, bn, nullptr, Amat, CAT_DIM, MTILES);

    // gather: Amat[:,256:512] = weighted h2 sums; R = sum eatt*rel; S = sum eatt
    k_gather<<<N_NODES, 128, 0, stream>>>(Amat, rel, natt, off, ecp, R, S);

    // Amat[:,512:640] = R @ Wr + S*br
    gemm_reg<128, 128><<<235, 512, 0, stream>>>(R, WrT, br, S, Amat + 2 * IN_DIM, CAT_DIM, MTILES);

    // out = relu(Amat @ Wa + ba)
    gemm_final<<<dim3(118, 2), 512, 0, stream>>>(Amat, WaT, ba, out);
}